// Round 19
// baseline (140.830 us; speedup 1.0000x reference)
//
#include <hip/hip_runtime.h>
#include <hip/hip_bf16.h>

#define NC 2048       // combined rows: [0,1024) = left, [1024,2048) = right
#define NPAIR 1048576

typedef __attribute__((ext_vector_type(8))) short bf16x8;
typedef __attribute__((ext_vector_type(4))) float f32x4;
typedef __attribute__((ext_vector_type(2))) float f32x2;
typedef __attribute__((ext_vector_type(4))) unsigned int u32x4;

__device__ inline short f2bf(float f) {
    __hip_bfloat16 h = __float2bfloat16(f);
    return __builtin_bit_cast(short, h);
}
__device__ inline unsigned cvt_pk(float a, float b) {   // lo=bf16(a), hi=bf16(b), RNE
    unsigned r;
    asm("v_cvt_pk_bf16_f32 %0, %1, %2" : "=v"(r) : "v"(a), "v"(b));
    return r;
}
__device__ inline float bfu_lo(unsigned u) { return __builtin_bit_cast(float, u << 16); }
__device__ inline float bfu_hi(unsigned u) { return __builtin_bit_cast(float, u & 0xFFFF0000u); }

// ---- hand-rolled grid barrier: agent-scope atomics + s_sleep spin (NOT cg::sync) ----
__device__ inline void gbar(unsigned* cnt, unsigned target) {
    __syncthreads();
    if (threadIdx.x == 0) {
        __hip_atomic_fetch_add(cnt, 1u, __ATOMIC_ACQ_REL, __HIP_MEMORY_SCOPE_AGENT);
        while (__hip_atomic_load(cnt, __ATOMIC_ACQUIRE, __HIP_MEMORY_SCOPE_AGENT) < target)
            __builtin_amdgcn_s_sleep(2);
    }
    __syncthreads();
}

// ---------------- layer phase body (r18-proven k_layer, as device fn) ----------------
template<int NIN, int K, int NOUT, bool FUSE_U, bool L1MODE>
__device__ void layer_body(int bid, int t,
        const float* __restrict__ xl, const float* __restrict__ xr,
        const int* __restrict__ ijl, const int* __restrict__ ijr,
        const float* __restrict__ el, const float* __restrict__ er,
        float* __restrict__ xejg,
        const float* __restrict__ Wc, const float* __restrict__ Wn, const float* __restrict__ We,
        const float* __restrict__ A1,
        float* __restrict__ Y, short* __restrict__ UBg,
        float* ct, float* wts, float* x3s, float* ubs) {
    const int KP = K + 4;
    int w = t >> 6, l = t & 63;
    int c0 = bid * 4;
    // x part
    if (NIN == 128) {
#pragma unroll
        for (int p = 0; p < 2; ++p) {
            int col = p * 2 + (t >> 7), d = t & 127;
            int c = c0 + col, n = c & 1023;
            const float* xp = (c < 1024) ? xl : xr;
            ct[col * KP + d] = xp[n * NIN + d];
        }
    } else {
        int col = t >> 6, d = t & 63;
        int c = c0 + col, n = c & 1023;
        const float* xp = (c < 1024) ? xl : xr;
        ct[col * KP + d] = xp[n * NIN + d];
    }
    // neighbor-mean (one wave per column; n wave-uniform)
    {
        int col = w, c = c0 + col, n = c & 1023;
        const float* xp = (c < 1024) ? xl : xr;
        const int* ijp = (c < 1024) ? ijl : ijr;
        int nb = __builtin_amdgcn_readfirstlane(n);
        if (NIN == 128) {
            int d2 = l * 2;
            float s0 = 0.f, s1 = 0.f;
#pragma unroll
            for (int k = 0; k < 32; ++k) {
                int nh = ijp[nb * 32 + k];                 // s_load (uniform)
                f32x2 v = *(const f32x2*)&xp[nh * NIN + d2];
                s0 += v[0]; s1 += v[1];
            }
            ct[col * KP + NIN + d2]     = s0 * (1.f / 32.f);
            ct[col * KP + NIN + d2 + 1] = s1 * (1.f / 32.f);
        } else {
            float s = 0.f;
#pragma unroll
            for (int k = 0; k < 32; ++k) {
                int nh = ijp[nb * 32 + k];
                s += xp[nh * NIN + l];
            }
            ct[col * KP + NIN + l] = s * (1.f / 32.f);
        }
        // edge-mean part
        if (L1MODE) {
            const float* e = ((c < 1024) ? el : er) + (c & 1023) * 1024;
            f32x4 s4 = {0.f, 0.f, 0.f, 0.f};
#pragma unroll
            for (int q = 0; q < 4; ++q) {
                f32x4 v = *(const f32x4*)(e + q * 256 + l * 4);
#pragma unroll
                for (int ee = 0; ee < 4; ++ee) s4[ee] += v[ee];
            }
#pragma unroll
            for (int m = 8; m < 64; m <<= 1) {
#pragma unroll
                for (int ee = 0; ee < 4; ++ee) s4[ee] += __shfl_xor(s4[ee], m, 64);
            }
            if (l < 8) {
#pragma unroll
                for (int ee = 0; ee < 4; ++ee) s4[ee] *= (1.f / 32.f);
                *(f32x4*)&ct[col * KP + 2 * NIN + l * 4] = s4;
                *(f32x4*)&xejg[c * 32 + l * 4] = s4;       // persist for L2/L3
            }
        } else {
            if (l < 32) ct[col * KP + 2 * NIN + l] = xejg[c * 32 + l];
        }
    }
    // GEMM: wave w owns column w; weights transposed on the fly into padded LDS chunks
    int col = w, c = c0 + col;
    float a0 = 0.f, a1 = 0.f;
    for (int d0 = 0; d0 < K; d0 += 64) {
        int cl = (K - d0 < 64) ? (K - d0) : 64;
        const float* Wsrc; int Ksrc, ds0;
        if (d0 < NIN)          { Wsrc = Wc; Ksrc = NIN; ds0 = d0; }
        else if (d0 < 2 * NIN) { Wsrc = Wn; Ksrc = NIN; ds0 = d0 - NIN; }
        else                   { Wsrc = We; Ksrc = 32;  ds0 = 0; }
        __syncthreads();                                   // gather done / prev chunk done
        int q4 = cl >> 2;
        for (int idx = t; idx < NOUT * q4; idx += 256) {
            int o = idx / q4, dq = idx % q4;
            f32x4 v = *(const f32x4*)&Wsrc[o * Ksrc + ds0 + dq * 4];
#pragma unroll
            for (int j = 0; j < 4; ++j)
                wts[(dq * 4 + j) * 129 + o] = v[j];        // 2-way banks: free
        }
        __syncthreads();
#pragma unroll 4
        for (int dd = 0; dd < cl; ++dd) {
            float xd = ct[col * KP + d0 + dd];             // uniform LDS broadcast
            a0 = fmaf(wts[dd * 129 + l], xd, a0);
            if (NOUT == 128) a1 = fmaf(wts[dd * 129 + 64 + l], xd, a1);
        }
    }
    if (NOUT == 128) {
        Y[c * 128 + l]      = fmaxf(a0, 0.f);
        Y[c * 128 + 64 + l] = fmaxf(a1, 0.f);
    } else if (!FUSE_U) {
        Y[c * 64 + l] = fmaxf(a0, 0.f);
    } else {
        // U = 0.5*A1 @ x3 ; A1 transposed on the fly (0.5 folded)
        x3s[col * 64 + l] = fmaxf(a0, 0.f);
        __syncthreads();
        for (int idx = t; idx < 128 * 16; idx += 256) {
            int o = idx / 16, dq = idx % 16;
            f32x4 v = *(const f32x4*)&A1[o * 64 + dq * 4];
#pragma unroll
            for (int j = 0; j < 4; ++j)
                wts[(dq * 4 + j) * 129 + o] = 0.5f * v[j];
        }
        __syncthreads();
        float u0 = 0.f, u1 = 0.f;
#pragma unroll 4
        for (int d = 0; d < 64; ++d) {
            float xd = x3s[col * 64 + d];
            u0 = fmaf(wts[d * 129 + l],      xd, u0);
            u1 = fmaf(wts[d * 129 + 64 + l], xd, u1);
        }
        Y[c * 128 + l]      = u0;
        Y[c * 128 + 64 + l] = u1;
        // UB: bf16 pre-swizzled copy (k_dense stages it with a pure linear copy).
        ubs[col * 128 + l]      = u0;
        ubs[col * 128 + 64 + l] = u1;
        __syncthreads();
        if (l < 16) {
            int j = c0 + w;                                // global row index
            const float* src = &ubs[w * 128 + l * 8];
            u32x4 pw;
            pw[0] = cvt_pk(src[0], src[1]);
            pw[1] = cvt_pk(src[2], src[3]);
            pw[2] = cvt_pk(src[4], src[5]);
            pw[3] = cvt_pk(src[6], src[7]);
            *(u32x4*)((char*)UBg + j * 256 + ((l * 16) ^ ((j & 7) << 4))) = pw;
        }
    }
}

// ---------------- single conv kernel: L1 -> bar -> L2 -> bar -> L3+U ----------------
__global__ void __launch_bounds__(256)
k_conv(const float* xnl, const float* xnr, const int* ijl, const int* ijr,
       const float* xel, const float* xer, float* xej,
       const float* Wc1, const float* Wn1, const float* We1,
       const float* Wc2, const float* Wn2, const float* We2,
       const float* Wc3, const float* Wn3, const float* We3,
       const float* A1, const float* A2, const float* A3, short* Bpp,
       float* XA, float* XB, float* U, short* UB, unsigned* bar) {
    __shared__ float ct[4 * 292];
    __shared__ float wts[64 * 129];
    __shared__ float x3s[4 * 64];
    __shared__ float ubs[4 * 128];
    int bid = blockIdx.x, t = threadIdx.x;

    // Bpp fragment prep folded into blocks 0..7 (phase 1)
    if (bid < 8) {
        int base = bid * 1280;
#pragma unroll
        for (int k = 0; k < 5; ++k) {
            int j = base + k * 256 + t;      // j in [0, 10240)
            if (j < 8192) {                  // A2 frags: permuted h2 rows
                int ktnt = j >> 9, l2 = (j >> 3) & 63, e2 = j & 7;
                int kt = ktnt >> 2, nt = ktnt & 3;
                int m = l2 & 15;
                int o = (nt >> 1) * 32 + (m >> 2) * 8 + (nt & 1) * 4 + (m & 3);
                int kk = kt * 32 + (l2 >> 4) * 8 + e2;
                Bpp[j] = f2bf(A2[o * 128 + kk]);
            } else {                         // A3 frags: hi/lo split
                int jj = j - 8192;
                int cp = jj >> 9, l2 = (jj >> 3) & 63, e2 = jj & 7;
                int cc = cp >> 1, p = cp & 1;
                int m = l2 & 15;
                int h2 = cc * 32 + (l2 >> 4) * 8 + e2;
                float v = (m < 2) ? A3[m * 64 + h2] : 0.f;
                short hi = f2bf(v);
                float vh = __bfloat162float(__builtin_bit_cast(__hip_bfloat16, hi));
                Bpp[j] = p ? f2bf(v - vh) : hi;
            }
        }
    }

    layer_body<64, 160, 128, false, true>(bid, t, xnl, xnr, ijl, ijr, xel, xer, xej,
                                          Wc1, Wn1, We1, nullptr, XA, nullptr,
                                          ct, wts, x3s, ubs);
    gbar(bar + 0, 512);
    layer_body<128, 288, 128, false, false>(bid, t, XA, XA + 1024 * 128, ijl, ijr,
                                            nullptr, nullptr, xej,
                                            Wc2, Wn2, We2, nullptr, XB, nullptr,
                                            ct, wts, x3s, ubs);
    gbar(bar + 1, 512);
    layer_body<128, 288, 64, true, false>(bid, t, XB, XB + 1024 * 128, ijl, ijr,
                                          nullptr, nullptr, xej,
                                          Wc3, Wn3, We3, A1, U, UB,
                                          ct, wts, x3s, ubs);
}

// ---------------- dense over 1M pairs: r18 proven version (39.4us, VGPR 60, 32KB LDS) ----------------
__global__ __launch_bounds__(256) void k_dense(const float* __restrict__ U,
                                               const short* __restrict__ UBg,
                                               const short* __restrict__ Bpp,
                                               float* __restrict__ out) {
    __shared__ short urb[64 * 128];          // 16KB bf16 Ur tile (pre-swizzled)
    __shared__ short bpls[8192];             // 16KB A2 fragment pool
    int t = threadIdx.x;
    int lane = t & 63;
    int w = t >> 6;
    int j0 = blockIdx.x * 64;
    int i  = blockIdx.y * 4 + w;
    int col = lane & 15, g = lane >> 4;

    // stage Ur tile: linear copy of 16KB (swizzle already applied at producer)
    {
        const u32x4* src = (const u32x4*)((const char*)UBg + (1024 + j0) * 256);
        u32x4* dst = (u32x4*)urb;
#pragma unroll
        for (int it = 0; it < 4; ++it)
            dst[t + it * 256] = src[t + it * 256];
    }
    // stage A2 fragment pool: 1024 x 16B
#pragma unroll
    for (int it = 0; it < 4; ++it) {
        int idx = t + it * 256;
        *(u32x4*)&bpls[idx * 8] = *(const u32x4*)&Bpp[idx * 8];
    }

    // Ul slice (persistent f32)
    f32x4 ulq[4][2];
#pragma unroll
    for (int kt = 0; kt < 4; ++kt) {
        const float* p = U + i * 128 + kt * 32 + g * 8;
        ulq[kt][0] = *(const f32x4*)p;
        ulq[kt][1] = *(const f32x4*)(p + 4);
    }
    // A3 frags from global (identical values; one-time, L2-cached)
    bf16x8 a3f[2][2];
#pragma unroll
    for (int c = 0; c < 2; ++c)
#pragma unroll
        for (int p = 0; p < 2; ++p)
            a3f[c][p] = *(const bf16x8*)&Bpp[8192 + ((c * 2 + p) * 64 + lane) * 8];

    __syncthreads();

    const f32x4 z4 = {0.f, 0.f, 0.f, 0.f};
    const int xr = (col & 7) << 4;           // row&7 == col&7 (rows step by 16)
    for (int jg = 0; jg < 4; ++jg) {
        unsigned bofs = 0;
        asm volatile("" : "+v"(bofs));       // opaque 0: block cross-jg CSE of frag reads
        int rbase = (jg * 16 + col) * 256;
        bf16x8 h1f[4];
#pragma unroll
        for (int kt = 0; kt < 4; ++kt) {
            u32x4 uw = *(const u32x4*)((const char*)urb + rbase + (((kt * 64) | (g * 16)) ^ xr));
            f32x4 ur0 = {bfu_lo(uw[0]), bfu_hi(uw[0]), bfu_lo(uw[1]), bfu_hi(uw[1])};
            f32x4 ur1 = {bfu_lo(uw[2]), bfu_hi(uw[2]), bfu_lo(uw[3]), bfu_hi(uw[3])};
            f32x4 s0 = __builtin_elementwise_max(ulq[kt][0] + ur0, z4);   // v_pk_add/max
            f32x4 s1 = __builtin_elementwise_max(ulq[kt][1] + ur1, z4);
            u32x4 pw;
            pw[0] = cvt_pk(s0[0], s0[1]);
            pw[1] = cvt_pk(s0[2], s0[3]);
            pw[2] = cvt_pk(s1[0], s1[1]);
            pw[3] = cvt_pk(s1[2], s1[3]);
            h1f[kt] = __builtin_bit_cast(bf16x8, pw);
        }
        f32x4 acc1[4] = {{0,0,0,0},{0,0,0,0},{0,0,0,0},{0,0,0,0}};
#pragma unroll
        for (int nt = 0; nt < 4; ++nt)
#pragma unroll
            for (int kt = 0; kt < 4; ++kt) {
                bf16x8 a2 = *(const bf16x8*)&bpls[bofs + ((kt * 4 + nt) * 64 + lane) * 8];
                acc1[nt] = __builtin_amdgcn_mfma_f32_16x16x32_bf16(a2, h1f[kt], acc1[nt], 0, 0, 0);
            }

        f32x4 accO = {0, 0, 0, 0};
#pragma unroll
        for (int c = 0; c < 2; ++c) {
            f32x4 r0 = __builtin_elementwise_max(acc1[2 * c],     z4);
            f32x4 r1 = __builtin_elementwise_max(acc1[2 * c + 1], z4);
            u32x4 pw;
            pw[0] = cvt_pk(r0[0], r0[1]);
            pw[1] = cvt_pk(r0[2], r0[3]);
            pw[2] = cvt_pk(r1[0], r1[1]);
            pw[3] = cvt_pk(r1[2], r1[3]);
            bf16x8 hb = __builtin_bit_cast(bf16x8, pw);
            accO = __builtin_amdgcn_mfma_f32_16x16x32_bf16(a3f[c][0], hb, accO, 0, 0, 0);
            accO = __builtin_amdgcn_mfma_f32_16x16x32_bf16(a3f[c][1], hb, accO, 0, 0, 0);
        }
        if (lane < 16) {
            int p = i * 1024 + j0 + jg * 16 + col;
            out[p]         = fmaxf(accO[0], 0.f);
            out[NPAIR + p] = fmaxf(accO[1], 0.f);
        }
    }
}

extern "C" void kernel_launch(void* const* d_in, const int* in_sizes, int n_in,
                              void* d_out, int out_size, void* d_ws, size_t ws_size,
                              hipStream_t stream) {
    const float* xnr = (const float*)d_in[0];
    const float* xer = (const float*)d_in[1];
    const int*   ijr = (const int*)  d_in[2];
    const float* xnl = (const float*)d_in[3];
    const float* xel = (const float*)d_in[4];
    const int*   ijl = (const int*)  d_in[5];
    const float* Wc1 = (const float*)d_in[6];
    const float* Wn1 = (const float*)d_in[7];
    const float* We1 = (const float*)d_in[8];
    const float* Wc2 = (const float*)d_in[9];
    const float* Wn2 = (const float*)d_in[10];
    const float* We2 = (const float*)d_in[11];
    const float* Wc3 = (const float*)d_in[12];
    const float* Wn3 = (const float*)d_in[13];
    const float* We3 = (const float*)d_in[14];
    const float* A1  = (const float*)d_in[15];
    const float* A2  = (const float*)d_in[16];
    const float* A3  = (const float*)d_in[17];
    float* out = (float*)d_out;

    float* ws  = (float*)d_ws;
    float* xej = ws;                    // 65536
    short* Bpp = (short*)(xej + 65536); // 10240 shorts = 5120 floats
    float* XA  = xej + 65536 + 5120;    // 2048*128 = 262144
    float* XB  = XA + 262144;           // 2048*128 = 262144
    float* U   = XB + 262144;           // 2048*128 = 262144
    short* UB  = (short*)(U + 262144);  // 2048*256 bytes
    unsigned* bar = (unsigned*)(U + 262144 + 131072);

    // zero barrier counters each replay (graph-safe async memset)
    hipMemsetAsync(bar, 0, 2 * sizeof(unsigned), stream);

    void* args[] = {
        (void*)&xnl, (void*)&xnr, (void*)&ijl, (void*)&ijr,
        (void*)&xel, (void*)&xer, (void*)&xej,
        (void*)&Wc1, (void*)&Wn1, (void*)&We1,
        (void*)&Wc2, (void*)&Wn2, (void*)&We2,
        (void*)&Wc3, (void*)&Wn3, (void*)&We3,
        (void*)&A1,  (void*)&A2,  (void*)&A3,  (void*)&Bpp,
        (void*)&XA,  (void*)&XB,  (void*)&U,   (void*)&UB, (void*)&bar
    };
    hipLaunchCooperativeKernel((void*)k_conv, dim3(512), dim3(256), args, 0, stream);
    k_dense<<<dim3(16, 256), 256, 0, stream>>>(U, UB, Bpp, out);
}

// Round 20
// 76.284 us; speedup vs baseline: 1.8461x; 1.8461x over previous
//
#include <hip/hip_runtime.h>
#include <hip/hip_bf16.h>

#define NC 2048       // combined rows: [0,1024) = left, [1024,2048) = right
#define NPAIR 1048576

typedef __attribute__((ext_vector_type(8))) short bf16x8;
typedef __attribute__((ext_vector_type(4))) float f32x4;
typedef __attribute__((ext_vector_type(2))) float f32x2;
typedef __attribute__((ext_vector_type(4))) unsigned int u32x4;

__device__ inline short f2bf(float f) {
    __hip_bfloat16 h = __float2bfloat16(f);
    return __builtin_bit_cast(short, h);
}
__device__ inline unsigned cvt_pk(float a, float b) {   // lo=bf16(a), hi=bf16(b), RNE
    unsigned r;
    asm("v_cvt_pk_bf16_f32 %0, %1, %2" : "=v"(r) : "v"(a), "v"(b));
    return r;
}
__device__ inline float bfu_lo(unsigned u) { return __builtin_bit_cast(float, u << 16); }
__device__ inline float bfu_hi(unsigned u) { return __builtin_bit_cast(float, u & 0xFFFF0000u); }

// ---------------- fused gather+GEMM layer: 4 cols/block, on-the-fly W transpose ----------------
// L1MODE: computes xej in-block (stores for L2/L3); extra blocks (bid>=512) prep Bpp frags.
// FUSE_U additionally emits UB = bf16 pre-swizzled copy of U rows (k_dense staging source).
template<int NIN, int K, int NOUT, bool FUSE_U, bool L1MODE>
__global__ __launch_bounds__(256) void k_layer(
        const float* __restrict__ xl, const float* __restrict__ xr,
        const int* __restrict__ ijl, const int* __restrict__ ijr,
        const float* __restrict__ el, const float* __restrict__ er,
        float* __restrict__ xejg,
        const float* __restrict__ Wc, const float* __restrict__ Wn, const float* __restrict__ We,
        const float* __restrict__ A1,
        const float* __restrict__ A2, const float* __restrict__ A3, short* __restrict__ Bpp,
        float* __restrict__ Y, short* __restrict__ UBg) {
    const int KP = K + 4;
    __shared__ float ct[4 * KP];
    __shared__ float wts[64 * 129];          // padded: transposed writes conflict-free
    __shared__ float x3s[4 * 64];
    __shared__ float ubs[4 * 128];
    int t = threadIdx.x;
    int w = t >> 6, l = t & 63;

    if (L1MODE && blockIdx.x >= 512) {       // Bpp fragment prep (dense consumes after L3)
        int base = (blockIdx.x - 512) * 1280;
#pragma unroll
        for (int k = 0; k < 5; ++k) {
            int j = base + k * 256 + t;      // j in [0, 10240)
            if (j < 8192) {                  // A2 frags: permuted h2 rows
                int ktnt = j >> 9, l2 = (j >> 3) & 63, e2 = j & 7;
                int kt = ktnt >> 2, nt = ktnt & 3;
                int m = l2 & 15;
                int o = (nt >> 1) * 32 + (m >> 2) * 8 + (nt & 1) * 4 + (m & 3);
                int kk = kt * 32 + (l2 >> 4) * 8 + e2;
                Bpp[j] = f2bf(A2[o * 128 + kk]);
            } else {                         // A3 frags: hi/lo split
                int jj = j - 8192;
                int cp = jj >> 9, l2 = (jj >> 3) & 63, e2 = jj & 7;
                int cc = cp >> 1, p = cp & 1;
                int m = l2 & 15;
                int h2 = cc * 32 + (l2 >> 4) * 8 + e2;
                float v = (m < 2) ? A3[m * 64 + h2] : 0.f;
                short hi = f2bf(v);
                float vh = __bfloat162float(__builtin_bit_cast(__hip_bfloat16, hi));
                Bpp[j] = p ? f2bf(v - vh) : hi;
            }
        }
        return;
    }

    int c0 = blockIdx.x * 4;
    // x part
    if (NIN == 128) {
#pragma unroll
        for (int p = 0; p < 2; ++p) {
            int col = p * 2 + (t >> 7), d = t & 127;
            int c = c0 + col, n = c & 1023;
            const float* xp = (c < 1024) ? xl : xr;
            ct[col * KP + d] = xp[n * NIN + d];
        }
    } else {
        int col = t >> 6, d = t & 63;
        int c = c0 + col, n = c & 1023;
        const float* xp = (c < 1024) ? xl : xr;
        ct[col * KP + d] = xp[n * NIN + d];
    }
    // neighbor-mean (one wave per column; n wave-uniform)
    {
        int col = w, c = c0 + col, n = c & 1023;
        const float* xp = (c < 1024) ? xl : xr;
        const int* ijp = (c < 1024) ? ijl : ijr;
        int nb = __builtin_amdgcn_readfirstlane(n);
        if (NIN == 128) {
            int d2 = l * 2;
            float s0 = 0.f, s1 = 0.f;
#pragma unroll
            for (int k = 0; k < 32; ++k) {
                int nh = ijp[nb * 32 + k];                 // s_load (uniform)
                f32x2 v = *(const f32x2*)&xp[nh * NIN + d2];
                s0 += v[0]; s1 += v[1];
            }
            ct[col * KP + NIN + d2]     = s0 * (1.f / 32.f);
            ct[col * KP + NIN + d2 + 1] = s1 * (1.f / 32.f);
        } else {
            float s = 0.f;
#pragma unroll
            for (int k = 0; k < 32; ++k) {
                int nh = ijp[nb * 32 + k];
                s += xp[nh * NIN + l];
            }
            ct[col * KP + NIN + l] = s * (1.f / 32.f);
        }
        // edge-mean part
        if (L1MODE) {
            const float* e = ((c < 1024) ? el : er) + (c & 1023) * 1024;
            f32x4 s4 = {0.f, 0.f, 0.f, 0.f};
#pragma unroll
            for (int q = 0; q < 4; ++q) {
                f32x4 v = *(const f32x4*)(e + q * 256 + l * 4);
#pragma unroll
                for (int ee = 0; ee < 4; ++ee) s4[ee] += v[ee];
            }
#pragma unroll
            for (int m = 8; m < 64; m <<= 1) {
#pragma unroll
                for (int ee = 0; ee < 4; ++ee) s4[ee] += __shfl_xor(s4[ee], m, 64);
            }
            if (l < 8) {
#pragma unroll
                for (int ee = 0; ee < 4; ++ee) s4[ee] *= (1.f / 32.f);
                *(f32x4*)&ct[col * KP + 2 * NIN + l * 4] = s4;
                *(f32x4*)&xejg[c * 32 + l * 4] = s4;       // persist for L2/L3
            }
        } else {
            if (l < 32) ct[col * KP + 2 * NIN + l] = xejg[c * 32 + l];
        }
    }
    // GEMM: wave w owns column w; weights transposed on the fly into padded LDS chunks
    int col = w, c = c0 + col;
    float a0 = 0.f, a1 = 0.f;
    for (int d0 = 0; d0 < K; d0 += 64) {
        int cl = (K - d0 < 64) ? (K - d0) : 64;
        const float* Wsrc; int Ksrc, ds0;
        if (d0 < NIN)          { Wsrc = Wc; Ksrc = NIN; ds0 = d0; }
        else if (d0 < 2 * NIN) { Wsrc = Wn; Ksrc = NIN; ds0 = d0 - NIN; }
        else                   { Wsrc = We; Ksrc = 32;  ds0 = 0; }
        __syncthreads();                                   // gather done / prev chunk done
        int q4 = cl >> 2;
        for (int idx = t; idx < NOUT * q4; idx += 256) {
            int o = idx / q4, dq = idx % q4;
            f32x4 v = *(const f32x4*)&Wsrc[o * Ksrc + ds0 + dq * 4];
#pragma unroll
            for (int j = 0; j < 4; ++j)
                wts[(dq * 4 + j) * 129 + o] = v[j];        // 2-way banks: free
        }
        __syncthreads();
#pragma unroll 4
        for (int dd = 0; dd < cl; ++dd) {
            float xd = ct[col * KP + d0 + dd];             // uniform LDS broadcast
            a0 = fmaf(wts[dd * 129 + l], xd, a0);
            if (NOUT == 128) a1 = fmaf(wts[dd * 129 + 64 + l], xd, a1);
        }
    }
    if (NOUT == 128) {
        Y[c * 128 + l]      = fmaxf(a0, 0.f);
        Y[c * 128 + 64 + l] = fmaxf(a1, 0.f);
    } else if (!FUSE_U) {
        Y[c * 64 + l] = fmaxf(a0, 0.f);
    } else {
        // U = 0.5*A1 @ x3 ; A1 transposed on the fly (0.5 folded)
        x3s[col * 64 + l] = fmaxf(a0, 0.f);
        __syncthreads();
        for (int idx = t; idx < 128 * 16; idx += 256) {
            int o = idx / 16, dq = idx % 16;
            f32x4 v = *(const f32x4*)&A1[o * 64 + dq * 4];
#pragma unroll
            for (int j = 0; j < 4; ++j)
                wts[(dq * 4 + j) * 129 + o] = 0.5f * v[j];
        }
        __syncthreads();
        float u0 = 0.f, u1 = 0.f;
#pragma unroll 4
        for (int d = 0; d < 64; ++d) {
            float xd = x3s[col * 64 + d];
            u0 = fmaf(wts[d * 129 + l],      xd, u0);
            u1 = fmaf(wts[d * 129 + 64 + l], xd, u1);
        }
        Y[c * 128 + l]      = u0;
        Y[c * 128 + 64 + l] = u1;
        // UB: bf16 pre-swizzled copy (k_dense stages it with a pure linear copy).
        ubs[col * 128 + l]      = u0;
        ubs[col * 128 + 64 + l] = u1;
        __syncthreads();
        if (l < 16) {
            int j = c0 + w;                                // global row index
            const float* src = &ubs[w * 128 + l * 8];
            u32x4 pw;
            pw[0] = cvt_pk(src[0], src[1]);                // same RNE as old k_dense staging
            pw[1] = cvt_pk(src[2], src[3]);
            pw[2] = cvt_pk(src[4], src[5]);
            pw[3] = cvt_pk(src[6], src[7]);
            *(u32x4*)((char*)UBg + j * 256 + ((l * 16) ^ ((j & 7) << 4))) = pw;
        }
    }
}

// ---------------- dense over 1M pairs: 32KB LDS (5 blocks/CU), copy-only staging ----------------
// urb staged by pure linear b128 copy from pre-swizzled bf16 UB (producer did the cvt+swizzle).
// bpls holds A2 frags only (16KB); a3f read once per wave from global Bpp (L2-cached).
__global__ __launch_bounds__(256) void k_dense(const float* __restrict__ U,
                                               const short* __restrict__ UBg,
                                               const short* __restrict__ Bpp,
                                               float* __restrict__ out) {
    __shared__ short urb[64 * 128];          // 16KB bf16 Ur tile (pre-swizzled)
    __shared__ short bpls[8192];             // 16KB A2 fragment pool
    int t = threadIdx.x;
    int lane = t & 63;
    int w = t >> 6;
    int j0 = blockIdx.x * 64;
    int i  = blockIdx.y * 4 + w;
    int col = lane & 15, g = lane >> 4;

    // stage Ur tile: linear copy of 16KB (swizzle already applied at producer)
    {
        const u32x4* src = (const u32x4*)((const char*)UBg + (1024 + j0) * 256);
        u32x4* dst = (u32x4*)urb;
#pragma unroll
        for (int it = 0; it < 4; ++it)
            dst[t + it * 256] = src[t + it * 256];
    }
    // stage A2 fragment pool: 1024 x 16B
#pragma unroll
    for (int it = 0; it < 4; ++it) {
        int idx = t + it * 256;
        *(u32x4*)&bpls[idx * 8] = *(const u32x4*)&Bpp[idx * 8];
    }

    // Ul slice (persistent f32)
    f32x4 ulq[4][2];
#pragma unroll
    for (int kt = 0; kt < 4; ++kt) {
        const float* p = U + i * 128 + kt * 32 + g * 8;
        ulq[kt][0] = *(const f32x4*)p;
        ulq[kt][1] = *(const f32x4*)(p + 4);
    }
    // A3 frags from global (identical values; one-time, L2-cached)
    bf16x8 a3f[2][2];
#pragma unroll
    for (int c = 0; c < 2; ++c)
#pragma unroll
        for (int p = 0; p < 2; ++p)
            a3f[c][p] = *(const bf16x8*)&Bpp[8192 + ((c * 2 + p) * 64 + lane) * 8];

    __syncthreads();

    const f32x4 z4 = {0.f, 0.f, 0.f, 0.f};
    const int xr = (col & 7) << 4;           // row&7 == col&7 (rows step by 16)
    for (int jg = 0; jg < 4; ++jg) {
        unsigned bofs = 0;
        asm volatile("" : "+v"(bofs));       // opaque 0: block cross-jg CSE of frag reads
        int rbase = (jg * 16 + col) * 256;
        bf16x8 h1f[4];
#pragma unroll
        for (int kt = 0; kt < 4; ++kt) {
            u32x4 uw = *(const u32x4*)((const char*)urb + rbase + (((kt * 64) | (g * 16)) ^ xr));
            f32x4 ur0 = {bfu_lo(uw[0]), bfu_hi(uw[0]), bfu_lo(uw[1]), bfu_hi(uw[1])};
            f32x4 ur1 = {bfu_lo(uw[2]), bfu_hi(uw[2]), bfu_lo(uw[3]), bfu_hi(uw[3])};
            f32x4 s0 = __builtin_elementwise_max(ulq[kt][0] + ur0, z4);   // v_pk_add/max
            f32x4 s1 = __builtin_elementwise_max(ulq[kt][1] + ur1, z4);
            u32x4 pw;
            pw[0] = cvt_pk(s0[0], s0[1]);
            pw[1] = cvt_pk(s0[2], s0[3]);
            pw[2] = cvt_pk(s1[0], s1[1]);
            pw[3] = cvt_pk(s1[2], s1[3]);
            h1f[kt] = __builtin_bit_cast(bf16x8, pw);
        }
        f32x4 acc1[4] = {{0,0,0,0},{0,0,0,0},{0,0,0,0},{0,0,0,0}};
#pragma unroll
        for (int nt = 0; nt < 4; ++nt)
#pragma unroll
            for (int kt = 0; kt < 4; ++kt) {
                bf16x8 a2 = *(const bf16x8*)&bpls[bofs + ((kt * 4 + nt) * 64 + lane) * 8];
                acc1[nt] = __builtin_amdgcn_mfma_f32_16x16x32_bf16(a2, h1f[kt], acc1[nt], 0, 0, 0);
            }

        f32x4 accO = {0, 0, 0, 0};
#pragma unroll
        for (int c = 0; c < 2; ++c) {
            f32x4 r0 = __builtin_elementwise_max(acc1[2 * c],     z4);
            f32x4 r1 = __builtin_elementwise_max(acc1[2 * c + 1], z4);
            u32x4 pw;
            pw[0] = cvt_pk(r0[0], r0[1]);
            pw[1] = cvt_pk(r0[2], r0[3]);
            pw[2] = cvt_pk(r1[0], r1[1]);
            pw[3] = cvt_pk(r1[2], r1[3]);
            bf16x8 hb = __builtin_bit_cast(bf16x8, pw);
            accO = __builtin_amdgcn_mfma_f32_16x16x32_bf16(a3f[c][0], hb, accO, 0, 0, 0);
            accO = __builtin_amdgcn_mfma_f32_16x16x32_bf16(a3f[c][1], hb, accO, 0, 0, 0);
        }
        if (lane < 16) {
            int p = i * 1024 + j0 + jg * 16 + col;
            out[p]         = fmaxf(accO[0], 0.f);
            out[NPAIR + p] = fmaxf(accO[1], 0.f);
        }
    }
}

extern "C" void kernel_launch(void* const* d_in, const int* in_sizes, int n_in,
                              void* d_out, int out_size, void* d_ws, size_t ws_size,
                              hipStream_t stream) {
    const float* xnr = (const float*)d_in[0];
    const float* xer = (const float*)d_in[1];
    const int*   ijr = (const int*)  d_in[2];
    const float* xnl = (const float*)d_in[3];
    const float* xel = (const float*)d_in[4];
    const int*   ijl = (const int*)  d_in[5];
    const float* Wc1 = (const float*)d_in[6];
    const float* Wn1 = (const float*)d_in[7];
    const float* We1 = (const float*)d_in[8];
    const float* Wc2 = (const float*)d_in[9];
    const float* Wn2 = (const float*)d_in[10];
    const float* We2 = (const float*)d_in[11];
    const float* Wc3 = (const float*)d_in[12];
    const float* Wn3 = (const float*)d_in[13];
    const float* We3 = (const float*)d_in[14];
    const float* A1  = (const float*)d_in[15];
    const float* A2  = (const float*)d_in[16];
    const float* A3  = (const float*)d_in[17];
    float* out = (float*)d_out;

    float* ws  = (float*)d_ws;
    float* xej = ws;                    // 65536
    short* Bpp = (short*)(xej + 65536); // 10240 shorts = 5120 floats
    float* XA  = xej + 65536 + 5120;    // 2048*128 = 262144
    float* XB  = XA + 262144;           // 2048*128 = 262144
    float* U   = XB + 262144;           // 2048*128 = 262144
    short* UB  = (short*)(U + 262144);  // 2048*256 bytes = 131072 floats

    // layer 1 (+ xej computation + Bpp prep in 8 extra blocks)
    k_layer<64, 160, 128, false, true><<<520, 256, 0, stream>>>(
        xnl, xnr, ijl, ijr, xel, xer, xej, Wc1, Wn1, We1, nullptr, A2, A3, Bpp, XA, nullptr);
    // layer 2
    k_layer<128, 288, 128, false, false><<<512, 256, 0, stream>>>(
        XA, XA + 1024 * 128, ijl, ijr, nullptr, nullptr, xej, Wc2, Wn2, We2, nullptr,
        nullptr, nullptr, nullptr, XB, nullptr);
    // layer 3 + U (+ UB bf16 pre-swizzled emission)
    k_layer<128, 288, 64, true, false><<<512, 256, 0, stream>>>(
        XB, XB + 1024 * 128, ijl, ijr, nullptr, nullptr, xej, Wc3, Wn3, We3, A1,
        nullptr, nullptr, nullptr, U, UB);
    // dense over all pairs
    k_dense<<<dim3(16, 256), 256, 0, stream>>>(U, UB, Bpp, out);
}

// Round 21
// 65.417 us; speedup vs baseline: 2.1528x; 1.1661x over previous
//
#include <hip/hip_runtime.h>
#include <hip/hip_bf16.h>

#define NC 2048       // combined rows: [0,1024) = left, [1024,2048) = right
#define NPAIR 1048576

typedef __attribute__((ext_vector_type(8))) short bf16x8;
typedef __attribute__((ext_vector_type(4))) float f32x4;
typedef __attribute__((ext_vector_type(2))) float f32x2;
typedef __attribute__((ext_vector_type(4))) unsigned int u32x4;

__device__ inline short f2bf(float f) {
    __hip_bfloat16 h = __float2bfloat16(f);
    return __builtin_bit_cast(short, h);
}
__device__ inline unsigned cvt_pk(float a, float b) {   // lo=bf16(a), hi=bf16(b), RNE
    unsigned r;
    asm("v_cvt_pk_bf16_f32 %0, %1, %2" : "=v"(r) : "v"(a), "v"(b));
    return r;
}
__device__ inline float bfu_lo(unsigned u) { return __builtin_bit_cast(float, u << 16); }
__device__ inline float bfu_hi(unsigned u) { return __builtin_bit_cast(float, u & 0xFFFF0000u); }

// ---------------- fused gather+GEMM layer: 4 cols/block ----------------
// Weights in [o][dd] LDS layout (pad 68) -> linear staging + b128 reads.
// Register-prefetch pipeline: chunk k+1 global loads issued under chunk k compute.
template<int NIN, int K, int NOUT, bool FUSE_U, bool L1MODE>
__global__ __launch_bounds__(256) void k_layer(
        const float* __restrict__ xl, const float* __restrict__ xr,
        const int* __restrict__ ijl, const int* __restrict__ ijr,
        const float* __restrict__ el, const float* __restrict__ er,
        float* __restrict__ xejg,
        const float* __restrict__ Wc, const float* __restrict__ Wn, const float* __restrict__ We,
        const float* __restrict__ A1,
        const float* __restrict__ A2, const float* __restrict__ A3, short* __restrict__ Bpp,
        float* __restrict__ Y, short* __restrict__ UBg) {
    const int KP = K + 4;
    const int NCH = (K + 63) / 64;
    __shared__ float ct[4 * KP];
    __shared__ float wts[128 * 68];          // [o][dd] pad-68: linear stage, b128 reads
    __shared__ float x3s[4 * 64];
    __shared__ float ubs[4 * 128];
    int t = threadIdx.x;
    int w = t >> 6, l = t & 63;

    if (L1MODE && blockIdx.x >= 512) {       // Bpp fragment prep (dense consumes after L3)
        int base = (blockIdx.x - 512) * 1280;
#pragma unroll
        for (int k = 0; k < 5; ++k) {
            int j = base + k * 256 + t;      // j in [0, 10240)
            if (j < 8192) {                  // A2 frags: permuted h2 rows
                int ktnt = j >> 9, l2 = (j >> 3) & 63, e2 = j & 7;
                int kt = ktnt >> 2, nt = ktnt & 3;
                int m = l2 & 15;
                int o = (nt >> 1) * 32 + (m >> 2) * 8 + (nt & 1) * 4 + (m & 3);
                int kk = kt * 32 + (l2 >> 4) * 8 + e2;
                Bpp[j] = f2bf(A2[o * 128 + kk]);
            } else {                         // A3 frags: hi/lo split
                int jj = j - 8192;
                int cp = jj >> 9, l2 = (jj >> 3) & 63, e2 = jj & 7;
                int cc = cp >> 1, p = cp & 1;
                int m = l2 & 15;
                int h2 = cc * 32 + (l2 >> 4) * 8 + e2;
                float v = (m < 2) ? A3[m * 64 + h2] : 0.f;
                short hi = f2bf(v);
                float vh = __bfloat162float(__builtin_bit_cast(__hip_bfloat16, hi));
                Bpp[j] = p ? f2bf(v - vh) : hi;
            }
        }
        return;
    }

    int c0 = blockIdx.x * 4;

    // chunk descriptor (constant-folds once the chunk loop is unrolled)
    auto chunk_src = [&](int c5, int& Ksrc, int& ds0, int& cl) -> const float* {
        int d0 = c5 * 64;
        cl = (K - d0 < 64) ? (K - d0) : 64;
        if (d0 < NIN)            { Ksrc = NIN; ds0 = d0;       return Wc; }
        else if (d0 < 2 * NIN)   { Ksrc = NIN; ds0 = d0 - NIN; return Wn; }
        else                     { Ksrc = 32;  ds0 = 0;        return We; }
    };
    f32x4 pf[8];
    auto prefetch = [&](int c5) {
        int Ksrc, ds0, cl;
        const float* Wsrc = chunk_src(c5, Ksrc, ds0, cl);
        int nel = cl * NOUT;
#pragma unroll
        for (int k = 0; k < 8; ++k) {
            int idx = t * 4 + k * 1024;
            if (idx < nel) {
                int o = idx / cl, dd = idx % cl;
                pf[k] = *(const f32x4*)&Wsrc[o * Ksrc + ds0 + dd];
            }
        }
    };
    auto commit = [&](int c5) {
        int Ksrc, ds0, cl;
        chunk_src(c5, Ksrc, ds0, cl);
        int nel = cl * NOUT;
#pragma unroll
        for (int k = 0; k < 8; ++k) {
            int idx = t * 4 + k * 1024;
            if (idx < nel) {
                int o = idx / cl, dd = idx % cl;
                *(f32x4*)&wts[o * 68 + dd] = pf[k];
            }
        }
    };

    prefetch(0);                             // issue chunk-0 weight loads early

    // x part
    if (NIN == 128) {
#pragma unroll
        for (int p = 0; p < 2; ++p) {
            int col = p * 2 + (t >> 7), d = t & 127;
            int c = c0 + col, n = c & 1023;
            const float* xp = (c < 1024) ? xl : xr;
            ct[col * KP + d] = xp[n * NIN + d];
        }
    } else {
        int col = t >> 6, d = t & 63;
        int c = c0 + col, n = c & 1023;
        const float* xp = (c < 1024) ? xl : xr;
        ct[col * KP + d] = xp[n * NIN + d];
    }
    // neighbor-mean (one wave per column; n wave-uniform)
    {
        int col = w, c = c0 + col, n = c & 1023;
        const float* xp = (c < 1024) ? xl : xr;
        const int* ijp = (c < 1024) ? ijl : ijr;
        int nb = __builtin_amdgcn_readfirstlane(n);
        if (NIN == 128) {
            int d2 = l * 2;
            float s0 = 0.f, s1 = 0.f;
#pragma unroll
            for (int k = 0; k < 32; ++k) {
                int nh = ijp[nb * 32 + k];                 // s_load (uniform)
                f32x2 v = *(const f32x2*)&xp[nh * NIN + d2];
                s0 += v[0]; s1 += v[1];
            }
            ct[col * KP + NIN + d2]     = s0 * (1.f / 32.f);
            ct[col * KP + NIN + d2 + 1] = s1 * (1.f / 32.f);
        } else {
            float s = 0.f;
#pragma unroll
            for (int k = 0; k < 32; ++k) {
                int nh = ijp[nb * 32 + k];
                s += xp[nh * NIN + l];
            }
            ct[col * KP + NIN + l] = s * (1.f / 32.f);
        }
        // edge-mean part
        if (L1MODE) {
            const float* e = ((c < 1024) ? el : er) + (c & 1023) * 1024;
            f32x4 s4 = {0.f, 0.f, 0.f, 0.f};
#pragma unroll
            for (int q = 0; q < 4; ++q) {
                f32x4 v = *(const f32x4*)(e + q * 256 + l * 4);
#pragma unroll
                for (int ee = 0; ee < 4; ++ee) s4[ee] += v[ee];
            }
#pragma unroll
            for (int m = 8; m < 64; m <<= 1) {
#pragma unroll
                for (int ee = 0; ee < 4; ++ee) s4[ee] += __shfl_xor(s4[ee], m, 64);
            }
            if (l < 8) {
#pragma unroll
                for (int ee = 0; ee < 4; ++ee) s4[ee] *= (1.f / 32.f);
                *(f32x4*)&ct[col * KP + 2 * NIN + l * 4] = s4;
                *(f32x4*)&xejg[c * 32 + l * 4] = s4;       // persist for L2/L3
            }
        } else {
            if (l < 32) ct[col * KP + 2 * NIN + l] = xejg[c * 32 + l];
        }
    }

    // GEMM: wave w owns column w; chunk pipeline: commit k, prefetch k+1, compute k.
    // FMA order identical to prior rounds -> bit-identical results.
    int col = w, c = c0 + col;
    float a0 = 0.f, a1 = 0.f;
#pragma unroll
    for (int c5 = 0; c5 < NCH; ++c5) {
        __syncthreads();                     // gather done (c5=0) / prev compute done
        commit(c5);                          // vmcnt-wait + LDS write
        if (c5 + 1 < NCH) prefetch(c5 + 1);  // issue next loads (no wait)
        __syncthreads();
        int d0 = c5 * 64;
        int cl = (K - d0 < 64) ? (K - d0) : 64;
#pragma unroll 4
        for (int dd = 0; dd < cl; dd += 4) {
            f32x4 cq = *(const f32x4*)&ct[col * KP + d0 + dd];   // uniform b128
            f32x4 w0 = *(const f32x4*)&wts[l * 68 + dd];         // b128, 2-way banks
            if (NOUT == 128) {
                f32x4 w1 = *(const f32x4*)&wts[(64 + l) * 68 + dd];
#pragma unroll
                for (int j = 0; j < 4; ++j) {
                    a0 = fmaf(w0[j], cq[j], a0);
                    a1 = fmaf(w1[j], cq[j], a1);
                }
            } else {
#pragma unroll
                for (int j = 0; j < 4; ++j)
                    a0 = fmaf(w0[j], cq[j], a0);
            }
        }
    }
    if (NOUT == 128) {
        Y[c * 128 + l]      = fmaxf(a0, 0.f);
        Y[c * 128 + 64 + l] = fmaxf(a1, 0.f);
    } else if (!FUSE_U) {
        Y[c * 64 + l] = fmaxf(a0, 0.f);
    } else {
        // U = 0.5*A1 @ x3 ; A1 staged linearly into [o][dd] layout (0.5 folded)
        x3s[col * 64 + l] = fmaxf(a0, 0.f);
        __syncthreads();
        for (int idx = t * 4; idx < 128 * 64; idx += 1024) {
            int o = idx >> 6, dd = idx & 63;
            f32x4 v = *(const f32x4*)&A1[o * 64 + dd];
#pragma unroll
            for (int j = 0; j < 4; ++j) v[j] *= 0.5f;
            *(f32x4*)&wts[o * 68 + dd] = v;
        }
        __syncthreads();
        float u0 = 0.f, u1 = 0.f;
#pragma unroll 4
        for (int d = 0; d < 64; d += 4) {
            f32x4 cq = *(const f32x4*)&x3s[col * 64 + d];
            f32x4 w0 = *(const f32x4*)&wts[l * 68 + d];
            f32x4 w1 = *(const f32x4*)&wts[(64 + l) * 68 + d];
#pragma unroll
            for (int j = 0; j < 4; ++j) {
                u0 = fmaf(w0[j], cq[j], u0);
                u1 = fmaf(w1[j], cq[j], u1);
            }
        }
        Y[c * 128 + l]      = u0;
        Y[c * 128 + 64 + l] = u1;
        // UB: bf16 pre-swizzled copy (k_dense stages it with a pure linear copy).
        ubs[col * 128 + l]      = u0;
        ubs[col * 128 + 64 + l] = u1;
        __syncthreads();
        if (l < 16) {
            int j = c0 + w;                                // global row index
            const float* src = &ubs[w * 128 + l * 8];
            u32x4 pw;
            pw[0] = cvt_pk(src[0], src[1]);                // same RNE as before
            pw[1] = cvt_pk(src[2], src[3]);
            pw[2] = cvt_pk(src[4], src[5]);
            pw[3] = cvt_pk(src[6], src[7]);
            *(u32x4*)((char*)UBg + j * 256 + ((l * 16) ^ ((j & 7) << 4))) = pw;
        }
    }
}

// ---------------- dense over 1M pairs: r18 proven (32KB LDS, copy-only staging) ----------------
__global__ __launch_bounds__(256) void k_dense(const float* __restrict__ U,
                                               const short* __restrict__ UBg,
                                               const short* __restrict__ Bpp,
                                               float* __restrict__ out) {
    __shared__ short urb[64 * 128];          // 16KB bf16 Ur tile (pre-swizzled)
    __shared__ short bpls[8192];             // 16KB A2 fragment pool
    int t = threadIdx.x;
    int lane = t & 63;
    int w = t >> 6;
    int j0 = blockIdx.x * 64;
    int i  = blockIdx.y * 4 + w;
    int col = lane & 15, g = lane >> 4;

    // stage Ur tile: linear copy of 16KB (swizzle already applied at producer)
    {
        const u32x4* src = (const u32x4*)((const char*)UBg + (1024 + j0) * 256);
        u32x4* dst = (u32x4*)urb;
#pragma unroll
        for (int it = 0; it < 4; ++it)
            dst[t + it * 256] = src[t + it * 256];
    }
    // stage A2 fragment pool: 1024 x 16B
#pragma unroll
    for (int it = 0; it < 4; ++it) {
        int idx = t + it * 256;
        *(u32x4*)&bpls[idx * 8] = *(const u32x4*)&Bpp[idx * 8];
    }

    // Ul slice (persistent f32)
    f32x4 ulq[4][2];
#pragma unroll
    for (int kt = 0; kt < 4; ++kt) {
        const float* p = U + i * 128 + kt * 32 + g * 8;
        ulq[kt][0] = *(const f32x4*)p;
        ulq[kt][1] = *(const f32x4*)(p + 4);
    }
    // A3 frags from global (identical values; one-time, L2-cached)
    bf16x8 a3f[2][2];
#pragma unroll
    for (int c = 0; c < 2; ++c)
#pragma unroll
        for (int p = 0; p < 2; ++p)
            a3f[c][p] = *(const bf16x8*)&Bpp[8192 + ((c * 2 + p) * 64 + lane) * 8];

    __syncthreads();

    const f32x4 z4 = {0.f, 0.f, 0.f, 0.f};
    const int xr = (col & 7) << 4;           // row&7 == col&7 (rows step by 16)
    for (int jg = 0; jg < 4; ++jg) {
        unsigned bofs = 0;
        asm volatile("" : "+v"(bofs));       // opaque 0: block cross-jg CSE of frag reads
        int rbase = (jg * 16 + col) * 256;
        bf16x8 h1f[4];
#pragma unroll
        for (int kt = 0; kt < 4; ++kt) {
            u32x4 uw = *(const u32x4*)((const char*)urb + rbase + (((kt * 64) | (g * 16)) ^ xr));
            f32x4 ur0 = {bfu_lo(uw[0]), bfu_hi(uw[0]), bfu_lo(uw[1]), bfu_hi(uw[1])};
            f32x4 ur1 = {bfu_lo(uw[2]), bfu_hi(uw[2]), bfu_lo(uw[3]), bfu_hi(uw[3])};
            f32x4 s0 = __builtin_elementwise_max(ulq[kt][0] + ur0, z4);   // v_pk_add/max
            f32x4 s1 = __builtin_elementwise_max(ulq[kt][1] + ur1, z4);
            u32x4 pw;
            pw[0] = cvt_pk(s0[0], s0[1]);
            pw[1] = cvt_pk(s0[2], s0[3]);
            pw[2] = cvt_pk(s1[0], s1[1]);
            pw[3] = cvt_pk(s1[2], s1[3]);
            h1f[kt] = __builtin_bit_cast(bf16x8, pw);
        }
        f32x4 acc1[4] = {{0,0,0,0},{0,0,0,0},{0,0,0,0},{0,0,0,0}};
#pragma unroll
        for (int nt = 0; nt < 4; ++nt)
#pragma unroll
            for (int kt = 0; kt < 4; ++kt) {
                bf16x8 a2 = *(const bf16x8*)&bpls[bofs + ((kt * 4 + nt) * 64 + lane) * 8];
                acc1[nt] = __builtin_amdgcn_mfma_f32_16x16x32_bf16(a2, h1f[kt], acc1[nt], 0, 0, 0);
            }

        f32x4 accO = {0, 0, 0, 0};
#pragma unroll
        for (int c = 0; c < 2; ++c) {
            f32x4 r0 = __builtin_elementwise_max(acc1[2 * c],     z4);
            f32x4 r1 = __builtin_elementwise_max(acc1[2 * c + 1], z4);
            u32x4 pw;
            pw[0] = cvt_pk(r0[0], r0[1]);
            pw[1] = cvt_pk(r0[2], r0[3]);
            pw[2] = cvt_pk(r1[0], r1[1]);
            pw[3] = cvt_pk(r1[2], r1[3]);
            bf16x8 hb = __builtin_bit_cast(bf16x8, pw);
            accO = __builtin_amdgcn_mfma_f32_16x16x32_bf16(a3f[c][0], hb, accO, 0, 0, 0);
            accO = __builtin_amdgcn_mfma_f32_16x16x32_bf16(a3f[c][1], hb, accO, 0, 0, 0);
        }
        if (lane < 16) {
            int p = i * 1024 + j0 + jg * 16 + col;
            out[p]         = fmaxf(accO[0], 0.f);
            out[NPAIR + p] = fmaxf(accO[1], 0.f);
        }
    }
}

extern "C" void kernel_launch(void* const* d_in, const int* in_sizes, int n_in,
                              void* d_out, int out_size, void* d_ws, size_t ws_size,
                              hipStream_t stream) {
    const float* xnr = (const float*)d_in[0];
    const float* xer = (const float*)d_in[1];
    const int*   ijr = (const int*)  d_in[2];
    const float* xnl = (const float*)d_in[3];
    const float* xel = (const float*)d_in[4];
    const int*   ijl = (const int*)  d_in[5];
    const float* Wc1 = (const float*)d_in[6];
    const float* Wn1 = (const float*)d_in[7];
    const float* We1 = (const float*)d_in[8];
    const float* Wc2 = (const float*)d_in[9];
    const float* Wn2 = (const float*)d_in[10];
    const float* We2 = (const float*)d_in[11];
    const float* Wc3 = (const float*)d_in[12];
    const float* Wn3 = (const float*)d_in[13];
    const float* We3 = (const float*)d_in[14];
    const float* A1  = (const float*)d_in[15];
    const float* A2  = (const float*)d_in[16];
    const float* A3  = (const float*)d_in[17];
    float* out = (float*)d_out;

    float* ws  = (float*)d_ws;
    float* xej = ws;                    // 65536
    short* Bpp = (short*)(xej + 65536); // 10240 shorts = 5120 floats
    float* XA  = xej + 65536 + 5120;    // 2048*128 = 262144
    float* XB  = XA + 262144;           // 2048*128 = 262144
    float* U   = XB + 262144;           // 2048*128 = 262144
    short* UB  = (short*)(U + 262144);  // 2048*256 bytes = 131072 floats

    // layer 1 (+ xej computation + Bpp prep in 8 extra blocks)
    k_layer<64, 160, 128, false, true><<<520, 256, 0, stream>>>(
        xnl, xnr, ijl, ijr, xel, xer, xej, Wc1, Wn1, We1, nullptr, A2, A3, Bpp, XA, nullptr);
    // layer 2
    k_layer<128, 288, 128, false, false><<<512, 256, 0, stream>>>(
        XA, XA + 1024 * 128, ijl, ijr, nullptr, nullptr, xej, Wc2, Wn2, We2, nullptr,
        nullptr, nullptr, nullptr, XB, nullptr);
    // layer 3 + U (+ UB bf16 pre-swizzled emission)
    k_layer<128, 288, 64, true, false><<<512, 256, 0, stream>>>(
        XB, XB + 1024 * 128, ijl, ijr, nullptr, nullptr, xej, Wc3, Wn3, We3, A1,
        nullptr, nullptr, nullptr, U, UB);
    // dense over all pairs
    k_dense<<<dim3(16, 256), 256, 0, stream>>>(U, UB, Bpp, out);
}

// Round 22
// 65.292 us; speedup vs baseline: 2.1569x; 1.0019x over previous
//
#include <hip/hip_runtime.h>
#include <hip/hip_bf16.h>

#define NC 2048       // combined rows: [0,1024) = left, [1024,2048) = right
#define NPAIR 1048576

typedef __attribute__((ext_vector_type(8))) short bf16x8;
typedef __attribute__((ext_vector_type(4))) float f32x4;
typedef __attribute__((ext_vector_type(2))) float f32x2;
typedef __attribute__((ext_vector_type(4))) unsigned int u32x4;

__device__ inline short f2bf(float f) {
    __hip_bfloat16 h = __float2bfloat16(f);
    return __builtin_bit_cast(short, h);
}
__device__ inline unsigned cvt_pk(float a, float b) {   // lo=bf16(a), hi=bf16(b), RNE
    unsigned r;
    asm("v_cvt_pk_bf16_f32 %0, %1, %2" : "=v"(r) : "v"(a), "v"(b));
    return r;
}
__device__ inline float bfu_lo(unsigned u) { return __builtin_bit_cast(float, u << 16); }
__device__ inline float bfu_hi(unsigned u) { return __builtin_bit_cast(float, u & 0xFFFF0000u); }

// ---------------- fused gather+GEMM layer: 4 cols/block (r21 proven) ----------------
// Weights in [o][dd] LDS layout (pad 68) -> linear staging + b128 reads.
// Register-prefetch pipeline: chunk k+1 global loads issued under chunk k compute.
template<int NIN, int K, int NOUT, bool FUSE_U, bool L1MODE>
__global__ __launch_bounds__(256) void k_layer(
        const float* __restrict__ xl, const float* __restrict__ xr,
        const int* __restrict__ ijl, const int* __restrict__ ijr,
        const float* __restrict__ el, const float* __restrict__ er,
        float* __restrict__ xejg,
        const float* __restrict__ Wc, const float* __restrict__ Wn, const float* __restrict__ We,
        const float* __restrict__ A1,
        const float* __restrict__ A2, const float* __restrict__ A3, short* __restrict__ Bpp,
        float* __restrict__ Y, short* __restrict__ UBg) {
    const int KP = K + 4;
    const int NCH = (K + 63) / 64;
    __shared__ float ct[4 * KP];
    __shared__ float wts[128 * 68];          // [o][dd] pad-68: linear stage, b128 reads
    __shared__ float x3s[4 * 64];
    __shared__ float ubs[4 * 128];
    int t = threadIdx.x;
    int w = t >> 6, l = t & 63;

    if (L1MODE && blockIdx.x >= 512) {       // Bpp fragment prep (dense consumes after L3)
        int base = (blockIdx.x - 512) * 1280;
#pragma unroll
        for (int k = 0; k < 5; ++k) {
            int j = base + k * 256 + t;      // j in [0, 10240)
            if (j < 8192) {                  // A2 frags: permuted h2 rows
                int ktnt = j >> 9, l2 = (j >> 3) & 63, e2 = j & 7;
                int kt = ktnt >> 2, nt = ktnt & 3;
                int m = l2 & 15;
                int o = (nt >> 1) * 32 + (m >> 2) * 8 + (nt & 1) * 4 + (m & 3);
                int kk = kt * 32 + (l2 >> 4) * 8 + e2;
                Bpp[j] = f2bf(A2[o * 128 + kk]);
            } else {                         // A3 frags: hi/lo split
                int jj = j - 8192;
                int cp = jj >> 9, l2 = (jj >> 3) & 63, e2 = jj & 7;
                int cc = cp >> 1, p = cp & 1;
                int m = l2 & 15;
                int h2 = cc * 32 + (l2 >> 4) * 8 + e2;
                float v = (m < 2) ? A3[m * 64 + h2] : 0.f;
                short hi = f2bf(v);
                float vh = __bfloat162float(__builtin_bit_cast(__hip_bfloat16, hi));
                Bpp[j] = p ? f2bf(v - vh) : hi;
            }
        }
        return;
    }

    int c0 = blockIdx.x * 4;

    auto chunk_src = [&](int c5, int& Ksrc, int& ds0, int& cl) -> const float* {
        int d0 = c5 * 64;
        cl = (K - d0 < 64) ? (K - d0) : 64;
        if (d0 < NIN)            { Ksrc = NIN; ds0 = d0;       return Wc; }
        else if (d0 < 2 * NIN)   { Ksrc = NIN; ds0 = d0 - NIN; return Wn; }
        else                     { Ksrc = 32;  ds0 = 0;        return We; }
    };
    f32x4 pf[8];
    auto prefetch = [&](int c5) {
        int Ksrc, ds0, cl;
        const float* Wsrc = chunk_src(c5, Ksrc, ds0, cl);
        int nel = cl * NOUT;
#pragma unroll
        for (int k = 0; k < 8; ++k) {
            int idx = t * 4 + k * 1024;
            if (idx < nel) {
                int o = idx / cl, dd = idx % cl;
                pf[k] = *(const f32x4*)&Wsrc[o * Ksrc + ds0 + dd];
            }
        }
    };
    auto commit = [&](int c5) {
        int Ksrc, ds0, cl;
        chunk_src(c5, Ksrc, ds0, cl);
        int nel = cl * NOUT;
#pragma unroll
        for (int k = 0; k < 8; ++k) {
            int idx = t * 4 + k * 1024;
            if (idx < nel) {
                int o = idx / cl, dd = idx % cl;
                *(f32x4*)&wts[o * 68 + dd] = pf[k];
            }
        }
    };

    prefetch(0);                             // issue chunk-0 weight loads early

    // x part
    if (NIN == 128) {
#pragma unroll
        for (int p = 0; p < 2; ++p) {
            int col = p * 2 + (t >> 7), d = t & 127;
            int c = c0 + col, n = c & 1023;
            const float* xp = (c < 1024) ? xl : xr;
            ct[col * KP + d] = xp[n * NIN + d];
        }
    } else {
        int col = t >> 6, d = t & 63;
        int c = c0 + col, n = c & 1023;
        const float* xp = (c < 1024) ? xl : xr;
        ct[col * KP + d] = xp[n * NIN + d];
    }
    // neighbor-mean (one wave per column; n wave-uniform)
    {
        int col = w, c = c0 + col, n = c & 1023;
        const float* xp = (c < 1024) ? xl : xr;
        const int* ijp = (c < 1024) ? ijl : ijr;
        int nb = __builtin_amdgcn_readfirstlane(n);
        if (NIN == 128) {
            int d2 = l * 2;
            float s0 = 0.f, s1 = 0.f;
#pragma unroll
            for (int k = 0; k < 32; ++k) {
                int nh = ijp[nb * 32 + k];                 // s_load (uniform)
                f32x2 v = *(const f32x2*)&xp[nh * NIN + d2];
                s0 += v[0]; s1 += v[1];
            }
            ct[col * KP + NIN + d2]     = s0 * (1.f / 32.f);
            ct[col * KP + NIN + d2 + 1] = s1 * (1.f / 32.f);
        } else {
            float s = 0.f;
#pragma unroll
            for (int k = 0; k < 32; ++k) {
                int nh = ijp[nb * 32 + k];
                s += xp[nh * NIN + l];
            }
            ct[col * KP + NIN + l] = s * (1.f / 32.f);
        }
        // edge-mean part
        if (L1MODE) {
            const float* e = ((c < 1024) ? el : er) + (c & 1023) * 1024;
            f32x4 s4 = {0.f, 0.f, 0.f, 0.f};
#pragma unroll
            for (int q = 0; q < 4; ++q) {
                f32x4 v = *(const f32x4*)(e + q * 256 + l * 4);
#pragma unroll
                for (int ee = 0; ee < 4; ++ee) s4[ee] += v[ee];
            }
#pragma unroll
            for (int m = 8; m < 64; m <<= 1) {
#pragma unroll
                for (int ee = 0; ee < 4; ++ee) s4[ee] += __shfl_xor(s4[ee], m, 64);
            }
            if (l < 8) {
#pragma unroll
                for (int ee = 0; ee < 4; ++ee) s4[ee] *= (1.f / 32.f);
                *(f32x4*)&ct[col * KP + 2 * NIN + l * 4] = s4;
                *(f32x4*)&xejg[c * 32 + l * 4] = s4;       // persist for L2/L3
            }
        } else {
            if (l < 32) ct[col * KP + 2 * NIN + l] = xejg[c * 32 + l];
        }
    }

    // GEMM: wave w owns column w; chunk pipeline: commit k, prefetch k+1, compute k.
    int col = w, c = c0 + col;
    float a0 = 0.f, a1 = 0.f;
#pragma unroll
    for (int c5 = 0; c5 < NCH; ++c5) {
        __syncthreads();                     // gather done (c5=0) / prev compute done
        commit(c5);                          // vmcnt-wait + LDS write
        if (c5 + 1 < NCH) prefetch(c5 + 1);  // issue next loads (no wait)
        __syncthreads();
        int d0 = c5 * 64;
        int cl = (K - d0 < 64) ? (K - d0) : 64;
#pragma unroll 4
        for (int dd = 0; dd < cl; dd += 4) {
            f32x4 cq = *(const f32x4*)&ct[col * KP + d0 + dd];   // uniform b128
            f32x4 w0 = *(const f32x4*)&wts[l * 68 + dd];         // b128, 2-way banks
            if (NOUT == 128) {
                f32x4 w1 = *(const f32x4*)&wts[(64 + l) * 68 + dd];
#pragma unroll
                for (int j = 0; j < 4; ++j) {
                    a0 = fmaf(w0[j], cq[j], a0);
                    a1 = fmaf(w1[j], cq[j], a1);
                }
            } else {
#pragma unroll
                for (int j = 0; j < 4; ++j)
                    a0 = fmaf(w0[j], cq[j], a0);
            }
        }
    }
    if (NOUT == 128) {
        Y[c * 128 + l]      = fmaxf(a0, 0.f);
        Y[c * 128 + 64 + l] = fmaxf(a1, 0.f);
    } else if (!FUSE_U) {
        Y[c * 64 + l] = fmaxf(a0, 0.f);
    } else {
        // U = 0.5*A1 @ x3 ; A1 staged linearly into [o][dd] layout (0.5 folded)
        x3s[col * 64 + l] = fmaxf(a0, 0.f);
        __syncthreads();
        for (int idx = t * 4; idx < 128 * 64; idx += 1024) {
            int o = idx >> 6, dd = idx & 63;
            f32x4 v = *(const f32x4*)&A1[o * 64 + dd];
#pragma unroll
            for (int j = 0; j < 4; ++j) v[j] *= 0.5f;
            *(f32x4*)&wts[o * 68 + dd] = v;
        }
        __syncthreads();
        float u0 = 0.f, u1 = 0.f;
#pragma unroll 4
        for (int d = 0; d < 64; d += 4) {
            f32x4 cq = *(const f32x4*)&x3s[col * 64 + d];
            f32x4 w0 = *(const f32x4*)&wts[l * 68 + d];
            f32x4 w1 = *(const f32x4*)&wts[(64 + l) * 68 + d];
#pragma unroll
            for (int j = 0; j < 4; ++j) {
                u0 = fmaf(w0[j], cq[j], u0);
                u1 = fmaf(w1[j], cq[j], u1);
            }
        }
        Y[c * 128 + l]      = u0;
        Y[c * 128 + 64 + l] = u1;
        // UB: bf16 pre-swizzled copy (k_dense stages it with a pure linear copy).
        ubs[col * 128 + l]      = u0;
        ubs[col * 128 + 64 + l] = u1;
        __syncthreads();
        if (l < 16) {
            int j = c0 + w;                                // global row index
            const float* src = &ubs[w * 128 + l * 8];
            u32x4 pw;
            pw[0] = cvt_pk(src[0], src[1]);                // same RNE as before
            pw[1] = cvt_pk(src[2], src[3]);
            pw[2] = cvt_pk(src[4], src[5]);
            pw[3] = cvt_pk(src[6], src[7]);
            *(u32x4*)((char*)UBg + j * 256 + ((l * 16) ^ ((j & 7) << 4))) = pw;
        }
    }
}

// ---------------- dense over 1M pairs: r18 structure + fully-unrolled jg loop ----------------
// #pragma unroll on jg: removes loop-carried WAR on h1f/acc1 and the backward branch,
// letting the compiler pipeline jg+1's LDS reads + h1-build under jg's MFMA latency.
// Per-jg bofs asm keeps A2 reads transient (prevents 64-reg re-hoist).
__global__ __launch_bounds__(256) void k_dense(const float* __restrict__ U,
                                               const short* __restrict__ UBg,
                                               const short* __restrict__ Bpp,
                                               float* __restrict__ out) {
    __shared__ short urb[64 * 128];          // 16KB bf16 Ur tile (pre-swizzled)
    __shared__ short bpls[8192];             // 16KB A2 fragment pool
    int t = threadIdx.x;
    int lane = t & 63;
    int w = t >> 6;
    int j0 = blockIdx.x * 64;
    int i  = blockIdx.y * 4 + w;
    int col = lane & 15, g = lane >> 4;

    // stage Ur tile: linear copy of 16KB (swizzle already applied at producer)
    {
        const u32x4* src = (const u32x4*)((const char*)UBg + (1024 + j0) * 256);
        u32x4* dst = (u32x4*)urb;
#pragma unroll
        for (int it = 0; it < 4; ++it)
            dst[t + it * 256] = src[t + it * 256];
    }
    // stage A2 fragment pool: 1024 x 16B
#pragma unroll
    for (int it = 0; it < 4; ++it) {
        int idx = t + it * 256;
        *(u32x4*)&bpls[idx * 8] = *(const u32x4*)&Bpp[idx * 8];
    }

    // Ul slice (persistent f32)
    f32x4 ulq[4][2];
#pragma unroll
    for (int kt = 0; kt < 4; ++kt) {
        const float* p = U + i * 128 + kt * 32 + g * 8;
        ulq[kt][0] = *(const f32x4*)p;
        ulq[kt][1] = *(const f32x4*)(p + 4);
    }
    // A3 frags from global (identical values; one-time, L2-cached)
    bf16x8 a3f[2][2];
#pragma unroll
    for (int c = 0; c < 2; ++c)
#pragma unroll
        for (int p = 0; p < 2; ++p)
            a3f[c][p] = *(const bf16x8*)&Bpp[8192 + ((c * 2 + p) * 64 + lane) * 8];

    __syncthreads();

    const f32x4 z4 = {0.f, 0.f, 0.f, 0.f};
    const int xr = (col & 7) << 4;           // row&7 == col&7 (rows step by 16)
#pragma unroll
    for (int jg = 0; jg < 4; ++jg) {
        unsigned bofs = 0;
        asm volatile("" : "+v"(bofs));       // opaque 0: keep A2 reads transient per jg
        int rbase = (jg * 16 + col) * 256;
        bf16x8 h1f[4];
#pragma unroll
        for (int kt = 0; kt < 4; ++kt) {
            u32x4 uw = *(const u32x4*)((const char*)urb + rbase + (((kt * 64) | (g * 16)) ^ xr));
            f32x4 ur0 = {bfu_lo(uw[0]), bfu_hi(uw[0]), bfu_lo(uw[1]), bfu_hi(uw[1])};
            f32x4 ur1 = {bfu_lo(uw[2]), bfu_hi(uw[2]), bfu_lo(uw[3]), bfu_hi(uw[3])};
            f32x4 s0 = __builtin_elementwise_max(ulq[kt][0] + ur0, z4);   // v_pk_add/max
            f32x4 s1 = __builtin_elementwise_max(ulq[kt][1] + ur1, z4);
            u32x4 pw;
            pw[0] = cvt_pk(s0[0], s0[1]);
            pw[1] = cvt_pk(s0[2], s0[3]);
            pw[2] = cvt_pk(s1[0], s1[1]);
            pw[3] = cvt_pk(s1[2], s1[3]);
            h1f[kt] = __builtin_bit_cast(bf16x8, pw);
        }
        f32x4 acc1[4] = {{0,0,0,0},{0,0,0,0},{0,0,0,0},{0,0,0,0}};
#pragma unroll
        for (int nt = 0; nt < 4; ++nt)
#pragma unroll
            for (int kt = 0; kt < 4; ++kt) {
                bf16x8 a2 = *(const bf16x8*)&bpls[bofs + ((kt * 4 + nt) * 64 + lane) * 8];
                acc1[nt] = __builtin_amdgcn_mfma_f32_16x16x32_bf16(a2, h1f[kt], acc1[nt], 0, 0, 0);
            }

        f32x4 accO = {0, 0, 0, 0};
#pragma unroll
        for (int c = 0; c < 2; ++c) {
            f32x4 r0 = __builtin_elementwise_max(acc1[2 * c],     z4);
            f32x4 r1 = __builtin_elementwise_max(acc1[2 * c + 1], z4);
            u32x4 pw;
            pw[0] = cvt_pk(r0[0], r0[1]);
            pw[1] = cvt_pk(r0[2], r0[3]);
            pw[2] = cvt_pk(r1[0], r1[1]);
            pw[3] = cvt_pk(r1[2], r1[3]);
            bf16x8 hb = __builtin_bit_cast(bf16x8, pw);
            accO = __builtin_amdgcn_mfma_f32_16x16x32_bf16(a3f[c][0], hb, accO, 0, 0, 0);
            accO = __builtin_amdgcn_mfma_f32_16x16x32_bf16(a3f[c][1], hb, accO, 0, 0, 0);
        }
        if (lane < 16) {
            int p = i * 1024 + j0 + jg * 16 + col;
            out[p]         = fmaxf(accO[0], 0.f);
            out[NPAIR + p] = fmaxf(accO[1], 0.f);
        }
    }
}

extern "C" void kernel_launch(void* const* d_in, const int* in_sizes, int n_in,
                              void* d_out, int out_size, void* d_ws, size_t ws_size,
                              hipStream_t stream) {
    const float* xnr = (const float*)d_in[0];
    const float* xer = (const float*)d_in[1];
    const int*   ijr = (const int*)  d_in[2];
    const float* xnl = (const float*)d_in[3];
    const float* xel = (const float*)d_in[4];
    const int*   ijl = (const int*)  d_in[5];
    const float* Wc1 = (const float*)d_in[6];
    const float* Wn1 = (const float*)d_in[7];
    const float* We1 = (const float*)d_in[8];
    const float* Wc2 = (const float*)d_in[9];
    const float* Wn2 = (const float*)d_in[10];
    const float* We2 = (const float*)d_in[11];
    const float* Wc3 = (const float*)d_in[12];
    const float* Wn3 = (const float*)d_in[13];
    const float* We3 = (const float*)d_in[14];
    const float* A1  = (const float*)d_in[15];
    const float* A2  = (const float*)d_in[16];
    const float* A3  = (const float*)d_in[17];
    float* out = (float*)d_out;

    float* ws  = (float*)d_ws;
    float* xej = ws;                    // 65536
    short* Bpp = (short*)(xej + 65536); // 10240 shorts = 5120 floats
    float* XA  = xej + 65536 + 5120;    // 2048*128 = 262144
    float* XB  = XA + 262144;           // 2048*128 = 262144
    float* U   = XB + 262144;           // 2048*128 = 262144
    short* UB  = (short*)(U + 262144);  // 2048*256 bytes = 131072 floats

    // layer 1 (+ xej computation + Bpp prep in 8 extra blocks)
    k_layer<64, 160, 128, false, true><<<520, 256, 0, stream>>>(
        xnl, xnr, ijl, ijr, xel, xer, xej, Wc1, Wn1, We1, nullptr, A2, A3, Bpp, XA, nullptr);
    // layer 2
    k_layer<128, 288, 128, false, false><<<512, 256, 0, stream>>>(
        XA, XA + 1024 * 128, ijl, ijr, nullptr, nullptr, xej, Wc2, Wn2, We2, nullptr,
        nullptr, nullptr, nullptr, XB, nullptr);
    // layer 3 + U (+ UB bf16 pre-swizzled emission)
    k_layer<128, 288, 64, true, false><<<512, 256, 0, stream>>>(
        XB, XB + 1024 * 128, ijl, ijr, nullptr, nullptr, xej, Wc3, Wn3, We3, A1,
        nullptr, nullptr, nullptr, U, UB);
    // dense over all pairs
    k_dense<<<dim3(16, 256), 256, 0, stream>>>(U, UB, Bpp, out);
}